// Round 16
// baseline (155.755 us; speedup 1.0000x reference)
//
#include <hip/hip_runtime.h>
#include <stdint.h>

#define THR  1.0f
#define BETA 0.95f
#define SX   4096.0f            // x scale (2^12) -> no fp16 denormal flush
#define SW   512.0f             // W scale (2^9)
#define SINV (1.0f / (4096.0f * 512.0f))
#define W1N  (128 * 784)

typedef __attribute__((ext_vector_type(8)))  _Float16 f16x8;
typedef __attribute__((ext_vector_type(16))) float    f32x16;
typedef __attribute__((ext_vector_type(4)))  float    fvec4;

__device__ __forceinline__ void gll16(const float* g, float* l){
  __builtin_amdgcn_global_load_lds((const __attribute__((address_space(1))) void*)g,
                                   (__attribute__((address_space(3))) void*)l, 16, 0, 0);
}

// 2-term RNE fp16 split of scaled W1 in per-16k fragment order:
// fragment (gks 0..48, nf 0..3, term 0..1) = 512 f16 (1KB); lane (kg*32+r)
// holds 8 f16 for col h=nf*32+r, k=gks*16+kg*8+0..7.
__global__ void split_w1(const float* __restrict__ W1, _Float16* __restrict__ wB){
  int i = blockIdx.x * 256 + threadIdx.x;
  if (i < W1N) {
    int h = i / 784, k = i % 784;
    float v = W1[i] * SW;
    _Float16 hi = (_Float16)v;
    _Float16 lo = (_Float16)(v - (float)hi);
    int ks = k >> 4, kg = (k >> 3) & 1, j = k & 7, nf = h >> 5, r = h & 31;
    int base = ((ks * 4 + nf) * 2) * 512 + (kg * 32 + r) * 8 + j;
    wB[base]       = hi;   // term 0
    wB[base + 512] = lo;   // term 1
  }
}

// cur1[m][h] = sum_k x[m][k]*W1[h][k] + b1[h] (scaled acc; bias in epilogue).
// Block: 4 waves, tile 128m x 128n. 24 slabs of 32-k + one 16-k tail.
// SINGLE fence per phase (24 barriers total, no lgkm drains):
//   phase s: STAGE(s+1) -> vmcnt(8) -> s_barrier -> CPH(s)
// Dbuf safety (m201-gap): phase s-1's ds_reads issue pre-barrier_s and sample
// LDS within ~120cy; slab s+1's LDS writes land >=200cy post-barrier_s.
// A fragment-major wave-private [0,8192); B fragment-major shared [8192,16384);
// A tail [16384,18432); B tail [18432,20480). 80KB -> 2 blocks/CU.
__launch_bounds__(256, 2)
__global__ void gemm1(const float* __restrict__ x,
                      const float* __restrict__ wBf,   // wB viewed as float*
                      const float* __restrict__ b1,
                      float* __restrict__ cur1,
                      long row0){
  __shared__ float lds[20480];
  const int lane = threadIdx.x & 63;
  const int w    = threadIdx.x >> 6;
  const long blk_row0 = row0 + (long)blockIdx.x * 128;
  const int r  = lane & 31;
  const int kg = lane >> 5;

  const float* xA = x + (blk_row0 + w * 32 + r) * 784 + kg * 8;  // wave's A rows

  // stage 32-k slab s (A wave-private fragment-major + B linear), 8 gll16/wave
  #define STAGE(p, s) {                                                      \
    _Pragma("unroll") for (int ksl = 0; ksl < 2; ++ksl) {                    \
      gll16(xA + (s) * 32 + ksl * 16,                                        \
            &lds[(p) * 4096 + w * 1024 + ksl * 512]);                        \
      gll16(xA + (s) * 32 + ksl * 16 + 4,                                    \
            &lds[(p) * 4096 + w * 1024 + ksl * 512 + 256]); }                \
    _Pragma("unroll") for (int i = 0; i < 4; ++i) {                          \
      int j = w * 4 + i;                                                     \
      gll16(wBf + (s) * 4096 + j * 256 + lane * 4,                           \
            &lds[8192 + (p) * 4096 + j * 256]); } }

  // one 16-k step from buffer p: 10 ds_read_b128 + split + 12 MFMA
  #define KSTEP(p, ksl) {                                                    \
    f16x8 b[8];                                                              \
    _Pragma("unroll") for (int f = 0; f < 8; ++f)                            \
      b[f] = *(const f16x8*)&lds[8192 + (p) * 4096 + ((ksl) * 8 + f) * 256 + lane * 4]; \
    fvec4 a0 = *(const fvec4*)&lds[(p) * 4096 + w * 1024 + (ksl) * 512 + lane * 4]; \
    fvec4 a1 = *(const fvec4*)&lds[(p) * 4096 + w * 1024 + (ksl) * 512 + 256 + lane * 4]; \
    f16x8 ah, al;                                                            \
    _Pragma("unroll") for (int j = 0; j < 8; ++j) {                          \
      float v = ((j < 4) ? a0[j] : a1[j - 4]) * SX;                          \
      _Float16 hh = (_Float16)v;                                             \
      ah[j] = hh; al[j] = (_Float16)(v - (float)hh);                         \
    }                                                                        \
    _Pragma("unroll") for (int nf = 0; nf < 4; ++nf) {                       \
      acc[nf] = __builtin_amdgcn_mfma_f32_32x32x16_f16(ah, b[nf * 2],     acc[nf], 0, 0, 0); \
      acc[nf] = __builtin_amdgcn_mfma_f32_32x32x16_f16(ah, b[nf * 2 + 1], acc[nf], 0, 0, 0); \
      acc[nf] = __builtin_amdgcn_mfma_f32_32x32x16_f16(al, b[nf * 2],     acc[nf], 0, 0, 0); \
    } }

  #define CPH(p) { KSTEP(p, 0); KSTEP(p, 1); }

  // single fence: counted vmcnt + barrier + compiler pins
  #define VMB(vm) {                                                          \
    asm volatile("s_waitcnt vmcnt(" #vm ")" ::: "memory");                   \
    __builtin_amdgcn_s_barrier();                                            \
    asm volatile("" ::: "memory");                                           \
    __builtin_amdgcn_sched_barrier(0); }

  f32x16 acc[4] = {};

  // ---- prologue: tails (A 2 + B 2 ops/wave) + slab 0 (8 ops) ----
  gll16(xA + 768,     &lds[16384 + w * 512]);
  gll16(xA + 768 + 4, &lds[16384 + w * 512 + 256]);
  #pragma unroll
  for (int i = 0; i < 2; ++i) {
    int j = w * 2 + i;
    gll16(wBf + 98304 + j * 256 + lane * 4, &lds[18432 + j * 256]);
  }
  STAGE(0, 0);

  // ---- 24 phases, one fence each; slab p -> buf p&1 ----
  for (int q = 0; q < 11; ++q) {
    const int s = 2 * q;
    STAGE(1, s + 1); VMB(8); CPH(0);    // phase s
    STAGE(0, s + 2); VMB(8); CPH(1);    // phase s+1
  }
  STAGE(1, 23); VMB(8); CPH(0);         // phase 22
  VMB(0); CPH(1);                       // phase 23 (drain)

  // ---- tail 16-k step (gks=48), data long since landed ----
  {
    f16x8 b[8];
    #pragma unroll
    for (int f = 0; f < 8; ++f)
      b[f] = *(const f16x8*)&lds[18432 + f * 256 + lane * 4];
    fvec4 a0 = *(const fvec4*)&lds[16384 + w * 512 + lane * 4];
    fvec4 a1 = *(const fvec4*)&lds[16384 + w * 512 + 256 + lane * 4];
    f16x8 ah, al;
    #pragma unroll
    for (int j = 0; j < 8; ++j) {
      float v = ((j < 4) ? a0[j] : a1[j - 4]) * SX;
      _Float16 hh = (_Float16)v;
      ah[j] = hh; al[j] = (_Float16)(v - (float)hh);
    }
    #pragma unroll
    for (int nf = 0; nf < 4; ++nf) {
      acc[nf] = __builtin_amdgcn_mfma_f32_32x32x16_f16(ah, b[nf * 2],     acc[nf], 0, 0, 0);
      acc[nf] = __builtin_amdgcn_mfma_f32_32x32x16_f16(ah, b[nf * 2 + 1], acc[nf], 0, 0, 0);
      acc[nf] = __builtin_amdgcn_mfma_f32_32x32x16_f16(al, b[nf * 2],     acc[nf], 0, 0, 0);
    }
  }

  // C/D layout (m74/m101-verified): col = lane&31, row = (reg&3)+8*(reg>>2)+4*(lane>>5)
  float b1v[4];
  #pragma unroll
  for (int nf = 0; nf < 4; ++nf) b1v[nf] = b1[nf * 32 + r];
  long m0 = (long)blockIdx.x * 128 + w * 32;
  #pragma unroll
  for (int nf = 0; nf < 4; ++nf)
    #pragma unroll
    for (int reg = 0; reg < 16; ++reg) {
      int rr = (reg & 3) + 8 * (reg >> 2) + 4 * kg;
      cur1[(m0 + rr) * 128 + nf * 32 + r] = acc[nf][reg] * SINV + b1v[nf];
    }
  #undef STAGE
  #undef KSTEP
  #undef CPH
  #undef VMB
}

// LIF recurrence + layer 2 (bias1 already folded into cur1).
__launch_bounds__(256)
__global__ void lif(const float* __restrict__ cur1,
                    const float* __restrict__ W2,
                    const float* __restrict__ b2,
                    float* __restrict__ out,
                    float* __restrict__ state1,
                    float* __restrict__ state2,
                    int t0, int tn){
  const int lane = threadIdx.x & 63;
  const int b = blockIdx.x * 4 + (threadIdx.x >> 6);
  const int o = lane & 15;
  const int c = lane >> 4;

  float wv[32];
  #pragma unroll
  for (int j = 0; j < 32; ++j) wv[j] = 0.f;
  if (o < 10) {
    #pragma unroll
    for (int j = 0; j < 32; ++j) wv[j] = W2[o * 128 + c * 32 + j];
  }
  float b2v = (lane < 10) ? b2[lane] : 0.f;

  float mem1a, mem1b, mem2;
  if (t0 == 0) { mem1a = 0.f; mem1b = 0.f; mem2 = 0.f; }
  else {
    mem1a = state1[b * 128 + lane];
    mem1b = state1[b * 128 + 64 + lane];
    mem2  = (lane < 10) ? state2[b * 10 + lane] : 0.f;
  }

  for (int t = t0; t < tn; ++t) {
    long base = ((long)(t - t0) * 4096 + b) * 128;
    float c1a = cur1[base + lane];
    float c1b = cur1[base + 64 + lane];
    float r1a = (mem1a > THR) ? THR : 0.f;
    float r1b = (mem1b > THR) ? THR : 0.f;
    mem1a = BETA * mem1a + c1a - r1a;
    mem1b = BETA * mem1b + c1b - r1b;

    uint64_t mA = __ballot(mem1a > THR);
    uint64_t mB = __ballot(mem1b > THR);
    uint64_t m64 = (c & 2) ? mB : mA;
    uint32_t bits = (uint32_t)(m64 >> ((c & 1) << 5));

    float s = 0.f;
    #pragma unroll
    for (int j = 0; j < 32; ++j)
      s = fmaf((float)((bits >> j) & 1u), wv[j], s);   // bfe+cvt+fma
    s += __shfl_xor(s, 16);
    s += __shfl_xor(s, 32);

    if (lane < 10) {
      float cur2 = s + b2v;
      float r2 = (mem2 > THR) ? THR : 0.f;
      mem2 = BETA * mem2 + cur2 - r2;
      float s2 = (mem2 > THR) ? 1.f : 0.f;
      long ob = (long)t * 40960 + (long)b * 10 + lane;
      out[ob] = s2;
      out[1228800 + ob] = mem2;
    }
  }

  if (tn < 30) {
    state1[b * 128 + lane] = mem1a;
    state1[b * 128 + 64 + lane] = mem1b;
    if (lane < 10) state2[b * 10 + lane] = mem2;
  }
}

extern "C" void kernel_launch(void* const* d_in, const int* in_sizes, int n_in,
                              void* d_out, int out_size, void* d_ws, size_t ws_size,
                              hipStream_t stream) {
  const float* x  = (const float*)d_in[0];
  const float* W1 = (const float*)d_in[1];
  const float* b1 = (const float*)d_in[2];
  const float* W2 = (const float*)d_in[3];
  const float* b2 = (const float*)d_in[4];
  float* out = (float*)d_out;

  const int T = 30, B = 4096;

  char* ws = (char*)d_ws;
  _Float16* wB = (_Float16*)ws;                  // 49*8*512 fp16 = 392KB
  size_t off = (size_t)49 * 8 * 512 * sizeof(_Float16);
  off = (off + 255) & ~(size_t)255;
  float* state1 = (float*)(ws + off); off += (size_t)B * 128 * 4;
  float* state2 = (float*)(ws + off); off += (size_t)B * 10 * 4;
  off = (off + 255) & ~(size_t)255;
  float* cur1 = (float*)(ws + off);

  size_t per_t = (size_t)B * 128 * 4;
  size_t avail = (ws_size > off) ? (ws_size - off) : 0;
  int CH = (int)(avail / per_t);
  if (CH > T) CH = T;
  if (CH < 1) CH = 1;

  split_w1<<<(W1N + 255) / 256, 256, 0, stream>>>(W1, wB);

  for (int t0 = 0; t0 < T; t0 += CH) {
    int tn = (t0 + CH < T) ? (t0 + CH) : T;
    int mrows = (tn - t0) * B;                   // multiple of 4096 -> multiple of 128
    gemm1<<<mrows / 128, 256, 0, stream>>>(x, (const float*)wB, b1, cur1, (long)t0 * B);
    lif<<<B / 4, 256, 0, stream>>>(cur1, W2, b2, out, state1, state2, t0, tn);
  }
}